// Round 6
// baseline (144.290 us; speedup 1.0000x reference)
//
#include <hip/hip_runtime.h>
#include <hip/hip_bf16.h>

#define NB  8
#define ENW 512
#define DEW 64
#define EMB 512
#define UN  512
#define NT  100

// k = 2*log2(e): folded into w_en, w_de, tw so that exp2(att2+bias2) = e^{2x}
#define KSCALE 2.8853900817779268f
#define L2E    1.4426950408889634f

typedef short bf16x8 __attribute__((ext_vector_type(8)));
typedef float f32x4  __attribute__((ext_vector_type(4)));

__device__ __forceinline__ unsigned short f2bf(float f) {   // RNE
    union { float f; unsigned int u; } v; v.f = f;
    unsigned int r = v.u + 0x7FFFu + ((v.u >> 16) & 1u);
    return (unsigned short)(r >> 16);
}

__device__ __forceinline__ unsigned short f2bf_fast(float f) {  // round-half-up
    union { float f; unsigned int u; } v; v.f = f;
    return (unsigned short)((v.u + 0x8000u) >> 16);
}

// ---------------- prep: weight transposes + topic bias + nu sums ----------------
// bx 0..63:    wen_t[u][e] = bf16(K*w_en[e][u])   (LDS tile transpose)
// bx 64..127:  wde_t[u][e] = bf16(K*w_de[e][u])
// bx 128..143: tw2[b][u] = K * sum_t topics[b][t]*wt[u][t]
// bx 144:      snu[0] = sum_u nu[u];  nu2[u] = -2*nu[u]
__global__ __launch_bounds__(256) void prep_kernel(const float* __restrict__ w_en,
                                                   const float* __restrict__ w_de,
                                                   const float* __restrict__ topics,
                                                   const float* __restrict__ wt_mat,
                                                   const float* __restrict__ nu,
                                                   unsigned short* __restrict__ wen_t,
                                                   unsigned short* __restrict__ wde_t,
                                                   float* __restrict__ tw2,
                                                   float* __restrict__ snu,
                                                   float* __restrict__ nu2) {
    const int bx = blockIdx.x, t = threadIdx.x;
    if (bx < 128) {
        __shared__ float tile[64][65];
        const float* w = (bx < 64) ? w_en : w_de;
        unsigned short* o = (bx < 64) ? wen_t : wde_t;
        const int tb = bx & 63;
        const int r0 = (tb >> 3) * 64;      // e-range
        const int c0 = (tb & 7) * 64;       // u-range
        const int rr = t >> 4, cc = (t & 15) * 4;
#pragma unroll
        for (int q = 0; q < 4; ++q) {
            float4 v = *(const float4*)(w + (size_t)(r0 + rr + 16 * q) * 512 + c0 + cc);
            *(float4*)&tile[rr + 16 * q][cc] = v;
        }
        __syncthreads();
#pragma unroll
        for (int q = 0; q < 4; ++q) {
            int ul = rr + 16 * q;
            int el = cc;
            ushort4 v;
            v.x = f2bf(KSCALE * tile[el][ul]);
            v.y = f2bf(KSCALE * tile[el + 1][ul]);
            v.z = f2bf(KSCALE * tile[el + 2][ul]);
            v.w = f2bf(KSCALE * tile[el + 3][ul]);
            *(ushort4*)(o + (size_t)(c0 + ul) * 512 + r0 + el) = v;
        }
    } else if (bx < 144) {
        int idx = (bx - 128) * 256 + t;      // b*512+u
        int b = idx >> 9, u = idx & 511;
        const float* tp = topics + b * NT;
        const float* wp = wt_mat + u * NT;
        float s = 0.f;
        for (int tt = 0; tt < NT; ++tt) s += tp[tt] * wp[tt];
        tw2[idx] = KSCALE * s;
    } else {
        __shared__ float red[256];
        float n0 = nu[t], n1 = nu[t + 256];
        nu2[t] = -2.f * n0;
        nu2[t + 256] = -2.f * n1;
        red[t] = n0 + n1;
        __syncthreads();
        for (int off = 128; off > 0; off >>= 1) {
            if (t < off) red[t] += red[t + off];
            __syncthreads();
        }
        if (t == 0) snu[0] = red[0];
    }
}

// ---------------- fused MFMA GEMM, f32 A with in-register bf16 cvt, exp2 epilogue ----
// bx<512:  Ea[m][u] = exp2(en[m]·wen_t^T)              (M=4096; mb=bx>>2, nq=bx&3)
// bx>=512: Eb[m][u] = exp2(de[m]·wde_t^T + tw2[b][u])  (M=512)
// block = 32m x 128n; wave = 16m x 64n (wave&1 -> m-half, wave>>1 -> n-half)
__global__ __launch_bounds__(256) void gemm_v2(const float* __restrict__ en,
                                               const float* __restrict__ de,
                                               const unsigned short* __restrict__ wen_t,
                                               const unsigned short* __restrict__ wde_t,
                                               const float* __restrict__ tw2,
                                               float* __restrict__ Ea,
                                               float* __restrict__ Eb) {
    const int K = 512, N = 512;
    const int bx = blockIdx.x;
    const bool is_de = (bx >= 512);
    const float* A = is_de ? de : en;
    const unsigned short* Bt = is_de ? wde_t : wen_t;
    float* C = is_de ? Eb : Ea;
    const int bb = is_de ? (bx - 512) : bx;
    const int mb = bb >> 2, nq = bb & 3;

    const int lane = threadIdx.x & 63;
    const int wave = threadIdx.x >> 6;
    const int m0 = mb * 32 + (wave & 1) * 16;
    const int n0 = nq * 128 + (wave >> 1) * 64;
    const int row = m0 + (lane & 15);
    const int kq  = (lane >> 4) * 8;

    f32x4 acc[4];
#pragma unroll
    for (int nn = 0; nn < 4; ++nn) acc[nn] = 0.f;

    const float* ap = A + (size_t)row * K + kq;
    const unsigned short* bp = Bt + (size_t)(n0 + (lane & 15)) * K + kq;
#pragma unroll 4
    for (int kc = 0; kc < K; kc += 32) {
        float4 a0 = *(const float4*)(ap + kc);
        float4 a1 = *(const float4*)(ap + kc + 4);
        bf16x8 a;
        a[0] = (short)f2bf_fast(a0.x); a[1] = (short)f2bf_fast(a0.y);
        a[2] = (short)f2bf_fast(a0.z); a[3] = (short)f2bf_fast(a0.w);
        a[4] = (short)f2bf_fast(a1.x); a[5] = (short)f2bf_fast(a1.y);
        a[6] = (short)f2bf_fast(a1.z); a[7] = (short)f2bf_fast(a1.w);
#pragma unroll
        for (int nn = 0; nn < 4; ++nn) {
            bf16x8 b = *(const bf16x8*)(bp + (size_t)nn * 16 * K + kc);
            acc[nn] = __builtin_amdgcn_mfma_f32_16x16x32_bf16(a, b, acc[nn], 0, 0, 0);
        }
    }
    const int crow = m0 + (lane >> 4) * 4;
    const int ccol = lane & 15;
#pragma unroll
    for (int nn = 0; nn < 4; ++nn)
#pragma unroll
        for (int r = 0; r < 4; ++r) {
            int rw = crow + r, cl = n0 + nn * 16 + ccol;
            float v = acc[nn][r];
            if (is_de) v += tw2[(rw >> 6) * 512 + cl];
            C[(size_t)rw * N + cl] = __builtin_amdgcn_exp2f(v);
        }
}

// ---------------- mu[b][j][i] = snu + sum_u nu2_u * rcp(Ea[b][i][u]*Eb[b][j][u] + 1) ----
__global__ __launch_bounds__(256) void mu4_kernel(const float* __restrict__ Ea,
                                                  const float* __restrict__ Eb,
                                                  const float* __restrict__ nu2,
                                                  const float* __restrict__ snu,
                                                  float* __restrict__ mu) {
    __shared__ float As[16][132];
    __shared__ float Bs[16][132];
    __shared__ float Ns[512];
    const int t = threadIdx.x;
    const int bx = blockIdx.x;
    const int jg = bx & 3;
    const int isplit = (bx >> 2) & 31;
    const int b = bx >> 7;
    const int i0 = isplit * 16, j0 = jg * 16;
    const int il = t & 15, jr = t >> 4;

    Ns[t] = nu2[t];
    Ns[t + 256] = nu2[t + 256];

    const float* aeb = Ea + (size_t)(b * ENW + i0) * UN;
    const float* bib = Eb + (size_t)(b * DEW + j0) * UN;

    float s0 = 0.f, s1 = 0.f;
    for (int uc = 0; uc < 512; uc += 128) {
#pragma unroll
        for (int q = 0; q < 2; ++q) {
            int idx = q * 256 + t;
            int row = idx >> 5, c4 = idx & 31;
            float4 va = *(const float4*)(aeb + (size_t)row * UN + uc + c4 * 4);
            *(float4*)&As[row][c4 * 4] = va;
            float4 vb = *(const float4*)(bib + (size_t)row * UN + uc + c4 * 4);
            *(float4*)&Bs[row][c4 * 4] = vb;
        }
        __syncthreads();
#pragma unroll 8
        for (int c = 0; c < 32; ++c) {
            float4 a  = *(const float4*)&As[il][c * 4];
            float4 bb = *(const float4*)&Bs[jr][c * 4];
            float4 nv = *(const float4*)&Ns[uc + c * 4];
            float e0 = fmaf(a.x, bb.x, 1.f);
            float e1 = fmaf(a.y, bb.y, 1.f);
            float e2 = fmaf(a.z, bb.z, 1.f);
            float e3 = fmaf(a.w, bb.w, 1.f);
            s0 = fmaf(nv.x, __builtin_amdgcn_rcpf(e0), s0);
            s1 = fmaf(nv.y, __builtin_amdgcn_rcpf(e1), s1);
            s0 = fmaf(nv.z, __builtin_amdgcn_rcpf(e2), s0);
            s1 = fmaf(nv.w, __builtin_amdgcn_rcpf(e3), s1);
        }
        __syncthreads();
    }
    mu[(size_t)(b * DEW + j0 + jr) * ENW + i0 + il] = snu[0] + s0 + s1;
}

// ---------------- fused softmax + p_gen + alphas + out ----------------
// grid 256: eh=bx&1, jq=(bx>>1)&15, b=bx>>5. 4 waves: phase1 wave=j (softmax);
// phase2 wave=i-quarter, lane=4e of this e-half; phase3 LDS cross-wave reduce.
__global__ __launch_bounds__(256) void softfin_kernel(const float* __restrict__ mu,
                                                      const float* __restrict__ en,
                                                      const float* __restrict__ de,
                                                      float* __restrict__ out,
                                                      float* __restrict__ alphas,
                                                      float* __restrict__ p_gen) {
    __shared__ float Al[4][512];
    __shared__ float Ps[4][4][256];
    const int bx = blockIdx.x;
    const int eh = bx & 1;
    const int jq = (bx >> 1) & 15;
    const int b  = bx >> 5;
    const int t = threadIdx.x;
    const int wave = t >> 6, lane = t & 63;
    const int j0 = jq * 4;

    // ---- phase 1: softmax for j = j0 + wave ----
    {
        const int bj = b * DEW + j0 + wave;
        const float* mup = mu + (size_t)bj * ENW;
        float v[8], a[8];
#pragma unroll
        for (int c = 0; c < 8; ++c) v[c] = mup[c * 64 + lane];
        float mx = v[0];
#pragma unroll
        for (int c = 1; c < 8; ++c) mx = fmaxf(mx, v[c]);
#pragma unroll
        for (int off = 32; off > 0; off >>= 1) mx = fmaxf(mx, __shfl_xor(mx, off));
        float s = 0.f;
#pragma unroll
        for (int c = 0; c < 8; ++c) { a[c] = __builtin_amdgcn_exp2f((v[c] - mx) * L2E); s += a[c]; }
#pragma unroll
        for (int off = 32; off > 0; off >>= 1) s += __shfl_xor(s, off);
        float inv = __builtin_amdgcn_rcpf(s);
#pragma unroll
        for (int c = 0; c < 8; ++c) {
            a[c] *= inv;
            Al[wave][c * 64 + lane] = a[c];
        }
        if (eh == 0) {
            float* alp = alphas + (size_t)bj * ENW;
            float* pgp = p_gen + (size_t)bj * ENW;
#pragma unroll
            for (int c = 0; c < 8; ++c) {
                alp[c * 64 + lane] = a[c];
                pgp[c * 64 + lane] = __builtin_amdgcn_rcpf(1.f + __builtin_amdgcn_exp2f(-v[c] * L2E));
            }
        }
    }
    __syncthreads();

    // ---- phase 2: partial sums over i-quarter `wave` ----
    const int i0 = wave * 128;
    const float* enb = en + (size_t)b * ENW * EMB + eh * 256 + lane * 4;
    f32x4 acc[4];
#pragma unroll
    for (int jj = 0; jj < 4; ++jj) acc[jj] = 0.f;
    for (int ig = 0; ig < 128; ig += 4) {
        const int ib = i0 + ig;
        float4 al0 = *(const float4*)&Al[0][ib];
        float4 al1 = *(const float4*)&Al[1][ib];
        float4 al2 = *(const float4*)&Al[2][ib];
        float4 al3 = *(const float4*)&Al[3][ib];
#pragma unroll
        for (int r = 0; r < 4; ++r) {
            float4 x = *(const float4*)(enb + (size_t)(ib + r) * EMB);
            float w0 = (r == 0) ? al0.x : (r == 1) ? al0.y : (r == 2) ? al0.z : al0.w;
            float w1 = (r == 0) ? al1.x : (r == 1) ? al1.y : (r == 2) ? al1.z : al1.w;
            float w2 = (r == 0) ? al2.x : (r == 1) ? al2.y : (r == 2) ? al2.z : al2.w;
            float w3 = (r == 0) ? al3.x : (r == 1) ? al3.y : (r == 2) ? al3.z : al3.w;
            acc[0][0] = fmaf(w0, x.x, acc[0][0]); acc[0][1] = fmaf(w0, x.y, acc[0][1]);
            acc[0][2] = fmaf(w0, x.z, acc[0][2]); acc[0][3] = fmaf(w0, x.w, acc[0][3]);
            acc[1][0] = fmaf(w1, x.x, acc[1][0]); acc[1][1] = fmaf(w1, x.y, acc[1][1]);
            acc[1][2] = fmaf(w1, x.z, acc[1][2]); acc[1][3] = fmaf(w1, x.w, acc[1][3]);
            acc[2][0] = fmaf(w2, x.x, acc[2][0]); acc[2][1] = fmaf(w2, x.y, acc[2][1]);
            acc[2][2] = fmaf(w2, x.z, acc[2][2]); acc[2][3] = fmaf(w2, x.w, acc[2][3]);
            acc[3][0] = fmaf(w3, x.x, acc[3][0]); acc[3][1] = fmaf(w3, x.y, acc[3][1]);
            acc[3][2] = fmaf(w3, x.z, acc[3][2]); acc[3][3] = fmaf(w3, x.w, acc[3][3]);
        }
    }
#pragma unroll
    for (int jj = 0; jj < 4; ++jj)
        *(f32x4*)&Ps[wave][jj][lane * 4] = acc[jj];
    __syncthreads();

    // ---- phase 3: reduce over i-quarters; wave handles its own j ----
    {
        const int bj = b * DEW + j0 + wave;
        const int e = eh * 256 + lane * 4;
        float4 p0 = *(const float4*)&Ps[0][wave][lane * 4];
        float4 p1 = *(const float4*)&Ps[1][wave][lane * 4];
        float4 p2 = *(const float4*)&Ps[2][wave][lane * 4];
        float4 p3 = *(const float4*)&Ps[3][wave][lane * 4];
        float4 d = *(const float4*)(de + (size_t)bj * EMB + e);
        float4 o;
        o.x = d.x + (p0.x + p1.x) + (p2.x + p3.x);
        o.y = d.y + (p0.y + p1.y) + (p2.y + p3.y);
        o.z = d.z + (p0.z + p1.z) + (p2.z + p3.z);
        o.w = d.w + (p0.w + p1.w) + (p2.w + p3.w);
        *(float4*)(out + (size_t)bj * EMB + e) = o;
    }
}

extern "C" void kernel_launch(void* const* d_in, const int* in_sizes, int n_in,
                              void* d_out, int out_size, void* d_ws, size_t ws_size,
                              hipStream_t stream) {
    const float* en     = (const float*)d_in[0];  // [8][512][512]
    const float* de     = (const float*)d_in[1];  // [8][64][512]
    const float* topics = (const float*)d_in[2];  // [8][100]
    const float* w_en   = (const float*)d_in[3];  // [512][512]
    const float* w_de   = (const float*)d_in[4];  // [512][512]
    const float* nu     = (const float*)d_in[5];  // [512]
    const float* wt     = (const float*)d_in[6];  // [512][100]

    float* out    = (float*)d_out;        // [8][64][512]
    float* alphas = out + 262144;
    float* p_gen  = out + 524288;

    char* ws = (char*)d_ws;
    float* Ea             = (float*)(ws);                       // 8388608 B
    float* Eb             = (float*)(ws + 8388608);             // 1048576 B
    float* tw2            = (float*)(ws + 9437184);             //   16384 B
    float* mu             = (float*)(ws + 9453568);             // 1048576 B
    unsigned short* wen_t = (unsigned short*)(ws + 10502144);   //  524288 B
    unsigned short* wde_t = (unsigned short*)(ws + 11026432);   //  524288 B
    float* snu            = (float*)(ws + 11550720);            //      16 B
    float* nu2            = (float*)(ws + 11550736);            //    2048 B

    prep_kernel<<<145, 256, 0, stream>>>(w_en, w_de, topics, wt, nu,
                                         wen_t, wde_t, tw2, snu, nu2);
    gemm_v2<<<576, 256, 0, stream>>>(en, de, wen_t, wde_t, tw2, Ea, Eb);
    mu4_kernel<<<1024, 256, 0, stream>>>(Ea, Eb, nu2, snu, mu);
    softfin_kernel<<<256, 256, 0, stream>>>(mu, en, de, out, alphas, p_gen);
}

// Round 7
// 140.585 us; speedup vs baseline: 1.0264x; 1.0264x over previous
//
#include <hip/hip_runtime.h>
#include <hip/hip_bf16.h>

#define NB  8
#define ENW 512
#define DEW 64
#define EMB 512
#define UN  512
#define NT  100

// k = 2*log2(e): folded into w_en, w_de, tw so that exp2(att2+bias2) = e^{2x}
#define KSCALE 2.8853900817779268f
#define L2E    1.4426950408889634f

typedef short bf16x8 __attribute__((ext_vector_type(8)));
typedef unsigned short u16x8 __attribute__((ext_vector_type(8)));
typedef float f32x4  __attribute__((ext_vector_type(4)));

__device__ __forceinline__ unsigned short f2bf(float f) {   // RNE
    union { float f; unsigned int u; } v; v.f = f;
    unsigned int r = v.u + 0x7FFFu + ((v.u >> 16) & 1u);
    return (unsigned short)(r >> 16);
}

// ---------------- fused prep ----------------
// bx 0..63:      wen_t[u][e] = bf16(K*w_en[e][u])   (LDS tile transpose)
// bx 64..127:    wde_t[u][e] = bf16(K*w_de[e][u])
// bx 128..1151:  en_bf = bf16(en)
// bx 1152..1279: de_bf = bf16(de)
// bx 1280..1295: tw2[b][u] = K * sum_t topics[b][t]*wt[u][t]
// bx 1296:       snu[0] = sum_u nu[u];  nu2[u] = -2*nu[u]
__global__ __launch_bounds__(256) void prep_kernel(const float* __restrict__ w_en,
                                                   const float* __restrict__ w_de,
                                                   const float* __restrict__ en,
                                                   const float* __restrict__ de,
                                                   const float* __restrict__ topics,
                                                   const float* __restrict__ wt_mat,
                                                   const float* __restrict__ nu,
                                                   unsigned short* __restrict__ wen_t,
                                                   unsigned short* __restrict__ wde_t,
                                                   unsigned short* __restrict__ en_bf,
                                                   unsigned short* __restrict__ de_bf,
                                                   float* __restrict__ tw2,
                                                   float* __restrict__ snu,
                                                   float* __restrict__ nu2) {
    const int bx = blockIdx.x, t = threadIdx.x;
    if (bx < 128) {
        __shared__ float tile[64][65];
        const float* w = (bx < 64) ? w_en : w_de;
        unsigned short* o = (bx < 64) ? wen_t : wde_t;
        const int tb = bx & 63;
        const int r0 = (tb >> 3) * 64;      // e-range
        const int c0 = (tb & 7) * 64;       // u-range
        const int rr = t >> 4, cc = (t & 15) * 4;
#pragma unroll
        for (int q = 0; q < 4; ++q) {
            float4 v = *(const float4*)(w + (size_t)(r0 + rr + 16 * q) * 512 + c0 + cc);
            *(float4*)&tile[rr + 16 * q][cc] = v;
        }
        __syncthreads();
#pragma unroll
        for (int q = 0; q < 4; ++q) {
            int ul = rr + 16 * q;
            int el = cc;
            ushort4 v;
            v.x = f2bf(KSCALE * tile[el][ul]);
            v.y = f2bf(KSCALE * tile[el + 1][ul]);
            v.z = f2bf(KSCALE * tile[el + 2][ul]);
            v.w = f2bf(KSCALE * tile[el + 3][ul]);
            *(ushort4*)(o + (size_t)(c0 + ul) * 512 + r0 + el) = v;
        }
    } else if (bx < 1280) {
        const bool is_en = (bx < 1152);
        const float* src = is_en ? en : de;
        unsigned short* dst = is_en ? en_bf : de_bf;
        const int idx = ((is_en ? (bx - 128) : (bx - 1152)) * 256 + t) * 8;
        float4 a0 = *(const float4*)(src + idx);
        float4 a1 = *(const float4*)(src + idx + 4);
        u16x8 o;
        o[0] = f2bf(a0.x); o[1] = f2bf(a0.y); o[2] = f2bf(a0.z); o[3] = f2bf(a0.w);
        o[4] = f2bf(a1.x); o[5] = f2bf(a1.y); o[6] = f2bf(a1.z); o[7] = f2bf(a1.w);
        *(u16x8*)(dst + idx) = o;
    } else if (bx < 1296) {
        int idx = (bx - 1280) * 256 + t;      // b*512+u
        int b = idx >> 9, u = idx & 511;
        const float* tp = topics + b * NT;
        const float* wp = wt_mat + u * NT;
        float s = 0.f;
        for (int tt = 0; tt < NT; ++tt) s += tp[tt] * wp[tt];
        tw2[idx] = KSCALE * s;
    } else {
        __shared__ float red[256];
        float n0 = nu[t], n1 = nu[t + 256];
        nu2[t] = -2.f * n0;
        nu2[t + 256] = -2.f * n1;
        red[t] = n0 + n1;
        __syncthreads();
        for (int off = 128; off > 0; off >>= 1) {
            if (t < off) red[t] += red[t + off];
            __syncthreads();
        }
        if (t == 0) snu[0] = red[0];
    }
}

// ---------------- fused MFMA GEMM (en + de), bf16 A, exp2 epilogue ----------------
// bx<64:  Ea[m][u] = exp2(en_bf[m]·wen_t^T)                   (M=4096)
// bx>=64: Eb[m][u] = exp2(de_bf[m]·wde_t^T + tw2[b][u])        (M=512)
__global__ __launch_bounds__(256) void gemm_fused(const unsigned short* __restrict__ en_bf,
                                                  const unsigned short* __restrict__ de_bf,
                                                  const unsigned short* __restrict__ wen_t,
                                                  const unsigned short* __restrict__ wde_t,
                                                  const float* __restrict__ tw2,
                                                  float* __restrict__ Ea,
                                                  float* __restrict__ Eb) {
    const int K = 512, N = 512;
    const int bx = blockIdx.x;
    const bool is_de = (bx >= 64);
    const unsigned short* A = is_de ? de_bf : en_bf;
    const unsigned short* Bt = is_de ? wde_t : wen_t;
    float* C = is_de ? Eb : Ea;
    const int mb = is_de ? (bx - 64) : bx;

    const int lane = threadIdx.x & 63;
    const int wave = threadIdx.x >> 6;
    const int m0 = mb * 64 + wave * 16;
    const int n0 = blockIdx.y * 64;
    const int row = m0 + (lane & 15);
    const int kq  = (lane >> 4) * 8;

    f32x4 acc[4];
#pragma unroll
    for (int nn = 0; nn < 4; ++nn) acc[nn] = 0.f;

    const unsigned short* ap = A + (size_t)row * K + kq;
    const unsigned short* bp = Bt + (size_t)(n0 + (lane & 15)) * K + kq;
#pragma unroll 4
    for (int kc = 0; kc < K; kc += 32) {
        bf16x8 a = *(const bf16x8*)(ap + kc);
#pragma unroll
        for (int nn = 0; nn < 4; ++nn) {
            bf16x8 b = *(const bf16x8*)(bp + (size_t)nn * 16 * K + kc);
            acc[nn] = __builtin_amdgcn_mfma_f32_16x16x32_bf16(a, b, acc[nn], 0, 0, 0);
        }
    }
    const int crow = m0 + (lane >> 4) * 4;
    const int ccol = lane & 15;
#pragma unroll
    for (int nn = 0; nn < 4; ++nn)
#pragma unroll
        for (int r = 0; r < 4; ++r) {
            int rw = crow + r, cl = n0 + nn * 16 + ccol;
            float v = acc[nn][r];
            if (is_de) v += tw2[(rw >> 6) * 512 + cl];
            C[(size_t)rw * N + cl] = __builtin_amdgcn_exp2f(v);
        }
}

// ---------------- mu[b][j][i] = snu + sum_u nu2_u * rcp(Ea[b][i][u]*Eb[b][j][u] + 1) ----
__global__ __launch_bounds__(256) void mu4_kernel(const float* __restrict__ Ea,
                                                  const float* __restrict__ Eb,
                                                  const float* __restrict__ nu2,
                                                  const float* __restrict__ snu,
                                                  float* __restrict__ mu) {
    __shared__ float As[16][132];
    __shared__ float Bs[16][132];
    __shared__ float Ns[512];
    const int t = threadIdx.x;
    const int bx = blockIdx.x;
    const int jg = bx & 3;
    const int isplit = (bx >> 2) & 31;
    const int b = bx >> 7;
    const int i0 = isplit * 16, j0 = jg * 16;
    const int il = t & 15, jr = t >> 4;

    Ns[t] = nu2[t];
    Ns[t + 256] = nu2[t + 256];

    const float* aeb = Ea + (size_t)(b * ENW + i0) * UN;
    const float* bib = Eb + (size_t)(b * DEW + j0) * UN;

    float s0 = 0.f, s1 = 0.f;
    for (int uc = 0; uc < 512; uc += 128) {
#pragma unroll
        for (int q = 0; q < 2; ++q) {
            int idx = q * 256 + t;
            int row = idx >> 5, c4 = idx & 31;
            float4 va = *(const float4*)(aeb + (size_t)row * UN + uc + c4 * 4);
            *(float4*)&As[row][c4 * 4] = va;
            float4 vb = *(const float4*)(bib + (size_t)row * UN + uc + c4 * 4);
            *(float4*)&Bs[row][c4 * 4] = vb;
        }
        __syncthreads();
#pragma unroll 8
        for (int c = 0; c < 32; ++c) {
            float4 a  = *(const float4*)&As[il][c * 4];
            float4 bb = *(const float4*)&Bs[jr][c * 4];
            float4 nv = *(const float4*)&Ns[uc + c * 4];
            float e0 = fmaf(a.x, bb.x, 1.f);
            float e1 = fmaf(a.y, bb.y, 1.f);
            float e2 = fmaf(a.z, bb.z, 1.f);
            float e3 = fmaf(a.w, bb.w, 1.f);
            s0 = fmaf(nv.x, __builtin_amdgcn_rcpf(e0), s0);
            s1 = fmaf(nv.y, __builtin_amdgcn_rcpf(e1), s1);
            s0 = fmaf(nv.z, __builtin_amdgcn_rcpf(e2), s0);
            s1 = fmaf(nv.w, __builtin_amdgcn_rcpf(e3), s1);
        }
        __syncthreads();
    }
    mu[(size_t)(b * DEW + j0 + jr) * ENW + i0 + il] = snu[0] + s0 + s1;
}

// ---------------- fused softmax + p_gen + alphas + out ----------------
// grid 256: eh=bx&1, jq=(bx>>1)&15, b=bx>>5. 4 waves: phase1 wave=j (softmax);
// phase2 wave=i-quarter, lane=4e of this e-half; phase3 LDS cross-wave reduce.
__global__ __launch_bounds__(256) void softfin_kernel(const float* __restrict__ mu,
                                                      const float* __restrict__ en,
                                                      const float* __restrict__ de,
                                                      float* __restrict__ out,
                                                      float* __restrict__ alphas,
                                                      float* __restrict__ p_gen) {
    __shared__ float Al[4][512];
    __shared__ float Ps[4][4][256];
    const int bx = blockIdx.x;
    const int eh = bx & 1;
    const int jq = (bx >> 1) & 15;
    const int b  = bx >> 5;
    const int t = threadIdx.x;
    const int wave = t >> 6, lane = t & 63;
    const int j0 = jq * 4;

    // ---- phase 1: softmax for j = j0 + wave ----
    {
        const int bj = b * DEW + j0 + wave;
        const float* mup = mu + (size_t)bj * ENW;
        float v[8], a[8];
#pragma unroll
        for (int c = 0; c < 8; ++c) v[c] = mup[c * 64 + lane];
        float mx = v[0];
#pragma unroll
        for (int c = 1; c < 8; ++c) mx = fmaxf(mx, v[c]);
#pragma unroll
        for (int off = 32; off > 0; off >>= 1) mx = fmaxf(mx, __shfl_xor(mx, off));
        float s = 0.f;
#pragma unroll
        for (int c = 0; c < 8; ++c) { a[c] = __builtin_amdgcn_exp2f((v[c] - mx) * L2E); s += a[c]; }
#pragma unroll
        for (int off = 32; off > 0; off >>= 1) s += __shfl_xor(s, off);
        float inv = __builtin_amdgcn_rcpf(s);
#pragma unroll
        for (int c = 0; c < 8; ++c) {
            a[c] *= inv;
            Al[wave][c * 64 + lane] = a[c];
        }
        if (eh == 0) {
            float* alp = alphas + (size_t)bj * ENW;
            float* pgp = p_gen + (size_t)bj * ENW;
#pragma unroll
            for (int c = 0; c < 8; ++c) {
                alp[c * 64 + lane] = a[c];
                pgp[c * 64 + lane] = __builtin_amdgcn_rcpf(1.f + __builtin_amdgcn_exp2f(-v[c] * L2E));
            }
        }
    }
    __syncthreads();

    // ---- phase 2: partial sums over i-quarter `wave` ----
    const int i0 = wave * 128;
    const float* enb = en + (size_t)b * ENW * EMB + eh * 256 + lane * 4;
    f32x4 acc[4];
#pragma unroll
    for (int jj = 0; jj < 4; ++jj) acc[jj] = 0.f;
    for (int ig = 0; ig < 128; ig += 4) {
        const int ib = i0 + ig;
        float4 al0 = *(const float4*)&Al[0][ib];
        float4 al1 = *(const float4*)&Al[1][ib];
        float4 al2 = *(const float4*)&Al[2][ib];
        float4 al3 = *(const float4*)&Al[3][ib];
#pragma unroll
        for (int r = 0; r < 4; ++r) {
            float4 x = *(const float4*)(enb + (size_t)(ib + r) * EMB);
            float w0 = (r == 0) ? al0.x : (r == 1) ? al0.y : (r == 2) ? al0.z : al0.w;
            float w1 = (r == 0) ? al1.x : (r == 1) ? al1.y : (r == 2) ? al1.z : al1.w;
            float w2 = (r == 0) ? al2.x : (r == 1) ? al2.y : (r == 2) ? al2.z : al2.w;
            float w3 = (r == 0) ? al3.x : (r == 1) ? al3.y : (r == 2) ? al3.z : al3.w;
            acc[0][0] = fmaf(w0, x.x, acc[0][0]); acc[0][1] = fmaf(w0, x.y, acc[0][1]);
            acc[0][2] = fmaf(w0, x.z, acc[0][2]); acc[0][3] = fmaf(w0, x.w, acc[0][3]);
            acc[1][0] = fmaf(w1, x.x, acc[1][0]); acc[1][1] = fmaf(w1, x.y, acc[1][1]);
            acc[1][2] = fmaf(w1, x.z, acc[1][2]); acc[1][3] = fmaf(w1, x.w, acc[1][3]);
            acc[2][0] = fmaf(w2, x.x, acc[2][0]); acc[2][1] = fmaf(w2, x.y, acc[2][1]);
            acc[2][2] = fmaf(w2, x.z, acc[2][2]); acc[2][3] = fmaf(w2, x.w, acc[2][3]);
            acc[3][0] = fmaf(w3, x.x, acc[3][0]); acc[3][1] = fmaf(w3, x.y, acc[3][1]);
            acc[3][2] = fmaf(w3, x.z, acc[3][2]); acc[3][3] = fmaf(w3, x.w, acc[3][3]);
        }
    }
#pragma unroll
    for (int jj = 0; jj < 4; ++jj)
        *(f32x4*)&Ps[wave][jj][lane * 4] = acc[jj];
    __syncthreads();

    // ---- phase 3: reduce over i-quarters; wave handles its own j ----
    {
        const int bj = b * DEW + j0 + wave;
        const int e = eh * 256 + lane * 4;
        float4 p0 = *(const float4*)&Ps[0][wave][lane * 4];
        float4 p1 = *(const float4*)&Ps[1][wave][lane * 4];
        float4 p2 = *(const float4*)&Ps[2][wave][lane * 4];
        float4 p3 = *(const float4*)&Ps[3][wave][lane * 4];
        float4 d = *(const float4*)(de + (size_t)bj * EMB + e);
        float4 o;
        o.x = d.x + (p0.x + p1.x) + (p2.x + p3.x);
        o.y = d.y + (p0.y + p1.y) + (p2.y + p3.y);
        o.z = d.z + (p0.z + p1.z) + (p2.z + p3.z);
        o.w = d.w + (p0.w + p1.w) + (p2.w + p3.w);
        *(float4*)(out + (size_t)bj * EMB + e) = o;
    }
}

extern "C" void kernel_launch(void* const* d_in, const int* in_sizes, int n_in,
                              void* d_out, int out_size, void* d_ws, size_t ws_size,
                              hipStream_t stream) {
    const float* en     = (const float*)d_in[0];  // [8][512][512]
    const float* de     = (const float*)d_in[1];  // [8][64][512]
    const float* topics = (const float*)d_in[2];  // [8][100]
    const float* w_en   = (const float*)d_in[3];  // [512][512]
    const float* w_de   = (const float*)d_in[4];  // [512][512]
    const float* nu     = (const float*)d_in[5];  // [512]
    const float* wt     = (const float*)d_in[6];  // [512][100]

    float* out    = (float*)d_out;        // [8][64][512]
    float* alphas = out + 262144;
    float* p_gen  = out + 524288;

    char* ws = (char*)d_ws;
    float* Ea             = (float*)(ws);                       // 8388608 B
    float* Eb             = (float*)(ws + 8388608);             // 1048576 B
    float* tw2            = (float*)(ws + 9437184);             //   16384 B
    float* mu             = (float*)(ws + 9453568);             // 1048576 B
    unsigned short* en_bf = (unsigned short*)(ws + 10502144);   // 4194304 B
    unsigned short* de_bf = (unsigned short*)(ws + 14696448);   //  524288 B
    unsigned short* wen_t = (unsigned short*)(ws + 15220736);   //  524288 B
    unsigned short* wde_t = (unsigned short*)(ws + 15745024);   //  524288 B
    float* snu            = (float*)(ws + 16269312);            //      16 B
    float* nu2            = (float*)(ws + 16269328);            //    2048 B

    prep_kernel<<<1297, 256, 0, stream>>>(w_en, w_de, en, de, topics, wt, nu,
                                          wen_t, wde_t, en_bf, de_bf, tw2, snu, nu2);
    gemm_fused<<<dim3(72, 8), 256, 0, stream>>>(en_bf, de_bf, wen_t, wde_t, tw2, Ea, Eb);
    mu4_kernel<<<1024, 256, 0, stream>>>(Ea, Eb, nu2, snu, mu);
    softfin_kernel<<<256, 256, 0, stream>>>(mu, en, de, out, alphas, p_gen);
}